// Round 1
// baseline (794.862 us; speedup 1.0000x reference)
//
#include <hip/hip_runtime.h>
#include <math.h>

#define DM 128
#define DI 256
#define DSN 64
#define NB 8
#define LSEQ 4096
#define NTOK (NB*LSEQ)
#define XDBL_LD 136

typedef float4 f4;

__device__ __forceinline__ float sigmoidf_(float x){ return 1.f/(1.f+__expf(-x)); }

// ---------------- LayerNorm stats (mu, rstd) per token ----------------
__global__ void __launch_bounds__(256) k_lnstats(const float* __restrict__ x, float* __restrict__ stats){
    int tok = blockIdx.x*4 + (threadIdx.x>>6);
    int lane = threadIdx.x & 63;
    const float* row = x + (size_t)tok*DM;
    float a = row[lane], b = row[lane+64];
    float s = a+b, ss = a*a+b*b;
    #pragma unroll
    for (int off=32; off>0; off>>=1){ s += __shfl_xor(s,off); ss += __shfl_xor(ss,off); }
    if (lane==0){
        float mu = s*(1.f/128.f);
        float var = ss*(1.f/128.f) - mu*mu;
        stats[tok*2+0] = mu;
        stats[tok*2+1] = rsqrtf(var + 1e-6f);
    }
}

// ---------------- fp32 tiled GEMM: C[M][N] = A[M][K] * Bw[N][K]^T ----------------
// MODE 0: A = LN(x) on the fly (in_proj). MODE 1: plain (x_proj). MODE 2: A is
// K-major transposed (ygT[(b*DI+k)*L + t]) + residual add (out_proj).
template<int N_DIM,int K_DIM,int MODE>
__global__ void __launch_bounds__(256) k_gemm(const float* __restrict__ Asrc,
    const float* __restrict__ Bw, float* __restrict__ Cout, int ldC,
    const float* __restrict__ stats, const float* __restrict__ nw,
    const float* __restrict__ nb, const float* __restrict__ resid)
{
    __shared__ float As[32][68];
    __shared__ float Bs[32][68];
    const int tid = threadIdx.x;
    const int m0 = blockIdx.x*64;
    const int n0 = blockIdx.y*64;
    float acc[4][4] = {{0.f,0.f,0.f,0.f},{0.f,0.f,0.f,0.f},{0.f,0.f,0.f,0.f},{0.f,0.f,0.f,0.f}};
    const int tm = (tid & 15)*4;
    const int tn = (tid >> 4)*4;

    for (int k0=0; k0<K_DIM; k0+=32){
        if (MODE==2){
            int kk = tid>>3;            // 0..31
            int mm = (tid&7)*8;         // 0..56
            int bb = m0 >> 12;          // m0 / 4096 (tile never crosses b: 64 | 4096)
            int t0 = m0 & (LSEQ-1);
            const float* src = Asrc + ((size_t)(bb*DI + k0 + kk))*LSEQ + t0 + mm;
            f4 v0 = *(const f4*)src, v1 = *(const f4*)(src+4);
            *(f4*)&As[kk][mm]   = v0;
            *(f4*)&As[kk][mm+4] = v1;
        } else {
            int mm = tid>>2;            // 0..63
            int kk = (tid&3)*8;         // 0,8,16,24
            int m = m0 + mm;
            const float* src = Asrc + (size_t)m*K_DIM + k0 + kk;
            f4 v0 = *(const f4*)src, v1 = *(const f4*)(src+4);
            if (MODE==0){
                float mu = stats[m*2+0], rs = stats[m*2+1];
                f4 w0 = *(const f4*)(nw+k0+kk), w1 = *(const f4*)(nw+k0+kk+4);
                f4 c0 = *(const f4*)(nb+k0+kk), c1 = *(const f4*)(nb+k0+kk+4);
                v0.x=(v0.x-mu)*rs*w0.x+c0.x; v0.y=(v0.y-mu)*rs*w0.y+c0.y;
                v0.z=(v0.z-mu)*rs*w0.z+c0.z; v0.w=(v0.w-mu)*rs*w0.w+c0.w;
                v1.x=(v1.x-mu)*rs*w1.x+c1.x; v1.y=(v1.y-mu)*rs*w1.y+c1.y;
                v1.z=(v1.z-mu)*rs*w1.z+c1.z; v1.w=(v1.w-mu)*rs*w1.w+c1.w;
            }
            As[kk+0][mm]=v0.x; As[kk+1][mm]=v0.y; As[kk+2][mm]=v0.z; As[kk+3][mm]=v0.w;
            As[kk+4][mm]=v1.x; As[kk+5][mm]=v1.y; As[kk+6][mm]=v1.z; As[kk+7][mm]=v1.w;
        }
        {
            int nn = tid>>2;
            int kk = (tid&3)*8;
            int n = n0 + nn;
            f4 v0 = {0.f,0.f,0.f,0.f}, v1 = {0.f,0.f,0.f,0.f};
            if (N_DIM%64==0 || n < N_DIM){
                const float* src = Bw + (size_t)n*K_DIM + k0 + kk;
                v0 = *(const f4*)src; v1 = *(const f4*)(src+4);
            }
            Bs[kk+0][nn]=v0.x; Bs[kk+1][nn]=v0.y; Bs[kk+2][nn]=v0.z; Bs[kk+3][nn]=v0.w;
            Bs[kk+4][nn]=v1.x; Bs[kk+5][nn]=v1.y; Bs[kk+6][nn]=v1.z; Bs[kk+7][nn]=v1.w;
        }
        __syncthreads();
        #pragma unroll
        for (int kk=0;kk<32;++kk){
            f4 av = *(const f4*)&As[kk][tm];
            f4 bv = *(const f4*)&Bs[kk][tn];
            acc[0][0]=fmaf(av.x,bv.x,acc[0][0]); acc[0][1]=fmaf(av.x,bv.y,acc[0][1]);
            acc[0][2]=fmaf(av.x,bv.z,acc[0][2]); acc[0][3]=fmaf(av.x,bv.w,acc[0][3]);
            acc[1][0]=fmaf(av.y,bv.x,acc[1][0]); acc[1][1]=fmaf(av.y,bv.y,acc[1][1]);
            acc[1][2]=fmaf(av.y,bv.z,acc[1][2]); acc[1][3]=fmaf(av.y,bv.w,acc[1][3]);
            acc[2][0]=fmaf(av.z,bv.x,acc[2][0]); acc[2][1]=fmaf(av.z,bv.y,acc[2][1]);
            acc[2][2]=fmaf(av.z,bv.z,acc[2][2]); acc[2][3]=fmaf(av.z,bv.w,acc[2][3]);
            acc[3][0]=fmaf(av.w,bv.x,acc[3][0]); acc[3][1]=fmaf(av.w,bv.y,acc[3][1]);
            acc[3][2]=fmaf(av.w,bv.z,acc[3][2]); acc[3][3]=fmaf(av.w,bv.w,acc[3][3]);
        }
        __syncthreads();
    }
    int n = n0 + tn;
    if (N_DIM%64==0 || n + 4 <= N_DIM){
        #pragma unroll
        for (int mi=0;mi<4;++mi){
            int m = m0+tm+mi;
            f4 v = {acc[mi][0],acc[mi][1],acc[mi][2],acc[mi][3]};
            if (MODE==2){
                f4 r = *(const f4*)(resid + (size_t)m*N_DIM + n);
                v.x+=r.x; v.y+=r.y; v.z+=r.z; v.w+=r.w;
            }
            *(f4*)(Cout + (size_t)m*ldC + n) = v;
        }
    }
}

// ---------------- causal depthwise conv (k=4) + SiLU ----------------
__global__ void __launch_bounds__(256) k_conv(const float* __restrict__ xz,
    const float* __restrict__ cw, const float* __restrict__ cb, float* __restrict__ u)
{
    int idx = blockIdx.x*256 + threadIdx.x;   // NTOK*64 threads, float4 over d
    int dq = idx & 63;
    int tok = idx >> 6;
    int t = tok & (LSEQ-1);
    f4 w0 = *(const f4*)(cw + (dq*4+0)*4);
    f4 w1 = *(const f4*)(cw + (dq*4+1)*4);
    f4 w2 = *(const f4*)(cw + (dq*4+2)*4);
    f4 w3 = *(const f4*)(cw + (dq*4+3)*4);
    f4 r  = *(const f4*)(cb + dq*4);
    #pragma unroll
    for (int j=0;j<4;++j){
        int tj = t-3+j;
        if (tj < 0) continue;
        f4 v = *(const f4*)(xz + (size_t)(tok-3+j)*(2*DI) + dq*4);
        r.x = fmaf(v.x, ((const float*)&w0)[j], r.x);
        r.y = fmaf(v.y, ((const float*)&w1)[j], r.y);
        r.z = fmaf(v.z, ((const float*)&w2)[j], r.z);
        r.w = fmaf(v.w, ((const float*)&w3)[j], r.w);
    }
    r.x *= sigmoidf_(r.x); r.y *= sigmoidf_(r.y);
    r.z *= sigmoidf_(r.z); r.w *= sigmoidf_(r.w);
    *(f4*)(u + (size_t)tok*DI + dq*4) = r;
}

// ---------------- delta = softplus(dt @ Wdt^T + bdt) ----------------
__global__ void __launch_bounds__(256) k_delta(const float* __restrict__ xdbl,
    const float* __restrict__ Wdt, const float* __restrict__ bdt, float* __restrict__ delta)
{
    int d = threadIdx.x;
    int tok0 = blockIdx.x * 16;
    f4 w0 = *(const f4*)(Wdt + d*8);
    f4 w1 = *(const f4*)(Wdt + d*8 + 4);
    float bias = bdt[d];
    __shared__ float dts[16][8];
    if (threadIdx.x < 128){
        int ti = threadIdx.x >> 3, r = threadIdx.x & 7;
        dts[ti][r] = xdbl[(size_t)(tok0+ti)*XDBL_LD + r];
    }
    __syncthreads();
    #pragma unroll 4
    for (int ti=0; ti<16; ++ti){
        f4 d0 = *(const f4*)&dts[ti][0];
        f4 d1 = *(const f4*)&dts[ti][4];
        float v = bias;
        v = fmaf(d0.x,w0.x, v); v = fmaf(d0.y,w0.y, v);
        v = fmaf(d0.z,w0.z, v); v = fmaf(d0.w,w0.w, v);
        v = fmaf(d1.x,w1.x, v); v = fmaf(d1.y,w1.y, v);
        v = fmaf(d1.z,w1.z, v); v = fmaf(d1.w,w1.w, v);
        float sp = (v > 20.f) ? v : log1pf(__expf(v));
        delta[(size_t)(tok0+ti)*DI + d] = sp;
    }
}

// ---------------- selective scan + gating, writes ygT[(b*DI+d)*L + t] ----------------
// one wave per (b,d); lane = state index n; chunked t by 64;
// y_t = sum_n h_n C_n via LDS transpose (write per step, column-sum per chunk).
__global__ void __launch_bounds__(64) k_scan(const float* __restrict__ delta,
    const float* __restrict__ u, const float* __restrict__ xz,
    const float* __restrict__ xdbl, const float* __restrict__ alog,
    const float* __restrict__ Dp, float* __restrict__ ygT)
{
    int bd = blockIdx.x;
    int d = bd & (DI-1);
    int b = bd >> 8;
    int lane = threadIdx.x;
    __shared__ float Q[64][65];
    float Acoef = -__expf(alog[d*DSN + lane]) * 1.44269504f;  // A * log2(e)
    float Dd = Dp[d];
    float h = 0.f;
    const float* xd_base = xdbl + (size_t)b*LSEQ*XDBL_LD;

    for (int c=0; c<LSEQ/64; ++c){
        int t0 = c*64;
        int tok = b*LSEQ + t0 + lane;
        float dv  = delta[(size_t)tok*DI + d];
        float uv  = u[(size_t)tok*DI + d];
        float duv = dv*uv;
        float zv  = xz[(size_t)tok*(2*DI) + DI + d];

        float Bpf[8], Cpf[8];
        #pragma unroll
        for (int k=0;k<8;++k){
            const float* row = xd_base + (size_t)(t0+k)*XDBL_LD;
            Bpf[k] = row[8 + lane];
            Cpf[k] = row[72 + lane];
        }
        #pragma unroll 1
        for (int jj=0; jj<8; ++jj){
            #pragma unroll
            for (int k=0;k<8;++k){
                int j = jj*8 + k;
                float Bn = Bpf[k], Cn = Cpf[k];
                int tnext = t0 + j + 8;
                tnext = tnext > (LSEQ-1) ? (LSEQ-1) : tnext;
                const float* row = xd_base + (size_t)tnext*XDBL_LD;
                Bpf[k] = row[8 + lane];
                Cpf[k] = row[72 + lane];
                float sd  = __int_as_float(__builtin_amdgcn_readlane(__float_as_int(dv),  j));
                float sdu = __int_as_float(__builtin_amdgcn_readlane(__float_as_int(duv), j));
                float a = exp2f(Acoef * sd);
                h = fmaf(a, h, sdu * Bn);
                Q[lane][j] = h * Cn;
            }
        }
        __syncthreads();
        float y = 0.f;
        #pragma unroll
        for (int n=0;n<64;++n) y += Q[n][lane];
        __syncthreads();
        float yfull = fmaf(uv, Dd, y);
        float yg = yfull * zv * sigmoidf_(zv);
        ygT[(size_t)bd*LSEQ + t0 + lane] = yg;
    }
}

extern "C" void kernel_launch(void* const* d_in, const int* in_sizes, int n_in,
                              void* d_out, int out_size, void* d_ws, size_t ws_size,
                              hipStream_t stream)
{
    (void)in_sizes; (void)n_in; (void)out_size; (void)ws_size;
    const float* x    = (const float*)d_in[0];
    const float* nw   = (const float*)d_in[1];
    const float* nb   = (const float*)d_in[2];
    const float* w_in = (const float*)d_in[3];
    const float* cw   = (const float*)d_in[4];
    const float* cb   = (const float*)d_in[5];
    const float* wx   = (const float*)d_in[6];
    const float* wdt  = (const float*)d_in[7];
    const float* bdt  = (const float*)d_in[8];
    const float* alog = (const float*)d_in[9];
    const float* Dp   = (const float*)d_in[10];
    const float* wo   = (const float*)d_in[11];
    float* out = (float*)d_out;

    float* ws    = (float*)d_ws;
    float* xz    = ws;                                 // NTOK*512
    float* u     = xz    + (size_t)NTOK*2*DI;          // NTOK*256
    float* xdbl  = u     + (size_t)NTOK*DI;            // NTOK*136
    float* delta = xdbl  + (size_t)NTOK*XDBL_LD;       // NTOK*256
    float* ygT   = delta + (size_t)NTOK*DI;            // NTOK*256
    float* stats = ygT   + (size_t)NTOK*DI;            // NTOK*2

    k_lnstats<<<NTOK/4, 256, 0, stream>>>(x, stats);

    dim3 g1(NTOK/64, 8);
    k_gemm<512,128,0><<<g1, 256, 0, stream>>>(x, w_in, xz, 512, stats, nw, nb, nullptr);

    k_conv<<<NTOK*64/256, 256, 0, stream>>>(xz, cw, cb, u);

    dim3 g2(NTOK/64, 3);
    k_gemm<136,256,1><<<g2, 256, 0, stream>>>(u, wx, xdbl, XDBL_LD, nullptr, nullptr, nullptr, nullptr);

    k_delta<<<NTOK/16, 256, 0, stream>>>(xdbl, wdt, bdt, delta);

    k_scan<<<NB*DI, 64, 0, stream>>>(delta, u, xz, xdbl, alog, Dp, ygT);

    dim3 g3(NTOK/64, 2);
    k_gemm<128,256,2><<<g3, 256, 0, stream>>>(ygT, wo, out, 128, nullptr, nullptr, nullptr, x);
}

// Round 2
// 626.338 us; speedup vs baseline: 1.2691x; 1.2691x over previous
//
#include <hip/hip_runtime.h>
#include <math.h>

#define DM 128
#define DI 256
#define DSN 64
#define NB 8
#define LSEQ 4096
#define NTOK (NB*LSEQ)
#define XDBL_LD 136
#define GRP 8
#define GLEN (LSEQ/GRP)   // 512

typedef float4 f4;

__device__ __forceinline__ float sigmoidf_(float x){ return 1.f/(1.f+__expf(-x)); }

// ---------------- LayerNorm stats (mu, rstd) per token ----------------
__global__ void __launch_bounds__(256) k_lnstats(const float* __restrict__ x, float* __restrict__ stats){
    int tok = blockIdx.x*4 + (threadIdx.x>>6);
    int lane = threadIdx.x & 63;
    const float* row = x + (size_t)tok*DM;
    float a = row[lane], b = row[lane+64];
    float s = a+b, ss = a*a+b*b;
    #pragma unroll
    for (int off=32; off>0; off>>=1){ s += __shfl_xor(s,off); ss += __shfl_xor(ss,off); }
    if (lane==0){
        float mu = s*(1.f/128.f);
        float var = ss*(1.f/128.f) - mu*mu;
        stats[tok*2+0] = mu;
        stats[tok*2+1] = rsqrtf(var + 1e-6f);
    }
}

// ---------------- fp32 tiled GEMM: C[M][N] = A[M][K] * Bw[N][K]^T ----------------
template<int N_DIM,int K_DIM,int MODE>
__global__ void __launch_bounds__(256) k_gemm(const float* __restrict__ Asrc,
    const float* __restrict__ Bw, float* __restrict__ Cout, int ldC,
    const float* __restrict__ stats, const float* __restrict__ nw,
    const float* __restrict__ nb, const float* __restrict__ resid)
{
    __shared__ float As[32][68];
    __shared__ float Bs[32][68];
    const int tid = threadIdx.x;
    const int m0 = blockIdx.x*64;
    const int n0 = blockIdx.y*64;
    float acc[4][4] = {{0.f,0.f,0.f,0.f},{0.f,0.f,0.f,0.f},{0.f,0.f,0.f,0.f},{0.f,0.f,0.f,0.f}};
    const int tm = (tid & 15)*4;
    const int tn = (tid >> 4)*4;

    for (int k0=0; k0<K_DIM; k0+=32){
        if (MODE==2){
            int kk = tid>>3;
            int mm = (tid&7)*8;
            int bb = m0 >> 12;
            int t0 = m0 & (LSEQ-1);
            const float* src = Asrc + ((size_t)(bb*DI + k0 + kk))*LSEQ + t0 + mm;
            f4 v0 = *(const f4*)src, v1 = *(const f4*)(src+4);
            *(f4*)&As[kk][mm]   = v0;
            *(f4*)&As[kk][mm+4] = v1;
        } else {
            int mm = tid>>2;
            int kk = (tid&3)*8;
            int m = m0 + mm;
            const float* src = Asrc + (size_t)m*K_DIM + k0 + kk;
            f4 v0 = *(const f4*)src, v1 = *(const f4*)(src+4);
            if (MODE==0){
                float mu = stats[m*2+0], rs = stats[m*2+1];
                f4 w0 = *(const f4*)(nw+k0+kk), w1 = *(const f4*)(nw+k0+kk+4);
                f4 c0 = *(const f4*)(nb+k0+kk), c1 = *(const f4*)(nb+k0+kk+4);
                v0.x=(v0.x-mu)*rs*w0.x+c0.x; v0.y=(v0.y-mu)*rs*w0.y+c0.y;
                v0.z=(v0.z-mu)*rs*w0.z+c0.z; v0.w=(v0.w-mu)*rs*w0.w+c0.w;
                v1.x=(v1.x-mu)*rs*w1.x+c1.x; v1.y=(v1.y-mu)*rs*w1.y+c1.y;
                v1.z=(v1.z-mu)*rs*w1.z+c1.z; v1.w=(v1.w-mu)*rs*w1.w+c1.w;
            }
            As[kk+0][mm]=v0.x; As[kk+1][mm]=v0.y; As[kk+2][mm]=v0.z; As[kk+3][mm]=v0.w;
            As[kk+4][mm]=v1.x; As[kk+5][mm]=v1.y; As[kk+6][mm]=v1.z; As[kk+7][mm]=v1.w;
        }
        {
            int nn = tid>>2;
            int kk = (tid&3)*8;
            int n = n0 + nn;
            f4 v0 = {0.f,0.f,0.f,0.f}, v1 = {0.f,0.f,0.f,0.f};
            if (N_DIM%64==0 || n < N_DIM){
                const float* src = Bw + (size_t)n*K_DIM + k0 + kk;
                v0 = *(const f4*)src; v1 = *(const f4*)(src+4);
            }
            Bs[kk+0][nn]=v0.x; Bs[kk+1][nn]=v0.y; Bs[kk+2][nn]=v0.z; Bs[kk+3][nn]=v0.w;
            Bs[kk+4][nn]=v1.x; Bs[kk+5][nn]=v1.y; Bs[kk+6][nn]=v1.z; Bs[kk+7][nn]=v1.w;
        }
        __syncthreads();
        #pragma unroll
        for (int kk=0;kk<32;++kk){
            f4 av = *(const f4*)&As[kk][tm];
            f4 bv = *(const f4*)&Bs[kk][tn];
            acc[0][0]=fmaf(av.x,bv.x,acc[0][0]); acc[0][1]=fmaf(av.x,bv.y,acc[0][1]);
            acc[0][2]=fmaf(av.x,bv.z,acc[0][2]); acc[0][3]=fmaf(av.x,bv.w,acc[0][3]);
            acc[1][0]=fmaf(av.y,bv.x,acc[1][0]); acc[1][1]=fmaf(av.y,bv.y,acc[1][1]);
            acc[1][2]=fmaf(av.y,bv.z,acc[1][2]); acc[1][3]=fmaf(av.y,bv.w,acc[1][3]);
            acc[2][0]=fmaf(av.z,bv.x,acc[2][0]); acc[2][1]=fmaf(av.z,bv.y,acc[2][1]);
            acc[2][2]=fmaf(av.z,bv.z,acc[2][2]); acc[2][3]=fmaf(av.z,bv.w,acc[2][3]);
            acc[3][0]=fmaf(av.w,bv.x,acc[3][0]); acc[3][1]=fmaf(av.w,bv.y,acc[3][1]);
            acc[3][2]=fmaf(av.w,bv.z,acc[3][2]); acc[3][3]=fmaf(av.w,bv.w,acc[3][3]);
        }
        __syncthreads();
    }
    int n = n0 + tn;
    if (N_DIM%64==0 || n + 4 <= N_DIM){
        #pragma unroll
        for (int mi=0;mi<4;++mi){
            int m = m0+tm+mi;
            f4 v = {acc[mi][0],acc[mi][1],acc[mi][2],acc[mi][3]};
            if (MODE==2){
                f4 r = *(const f4*)(resid + (size_t)m*N_DIM + n);
                v.x+=r.x; v.y+=r.y; v.z+=r.z; v.w+=r.w;
            }
            *(f4*)(Cout + (size_t)m*ldC + n) = v;
        }
    }
}

// ---------------- causal depthwise conv (k=4) + SiLU ----------------
__global__ void __launch_bounds__(256) k_conv(const float* __restrict__ xz,
    const float* __restrict__ cw, const float* __restrict__ cb, float* __restrict__ u)
{
    int idx = blockIdx.x*256 + threadIdx.x;
    int dq = idx & 63;
    int tok = idx >> 6;
    int t = tok & (LSEQ-1);
    f4 w0 = *(const f4*)(cw + (dq*4+0)*4);
    f4 w1 = *(const f4*)(cw + (dq*4+1)*4);
    f4 w2 = *(const f4*)(cw + (dq*4+2)*4);
    f4 w3 = *(const f4*)(cw + (dq*4+3)*4);
    f4 r  = *(const f4*)(cb + dq*4);
    #pragma unroll
    for (int j=0;j<4;++j){
        int tj = t-3+j;
        if (tj < 0) continue;
        f4 v = *(const f4*)(xz + (size_t)(tok-3+j)*(2*DI) + dq*4);
        r.x = fmaf(v.x, ((const float*)&w0)[j], r.x);
        r.y = fmaf(v.y, ((const float*)&w1)[j], r.y);
        r.z = fmaf(v.z, ((const float*)&w2)[j], r.z);
        r.w = fmaf(v.w, ((const float*)&w3)[j], r.w);
    }
    r.x *= sigmoidf_(r.x); r.y *= sigmoidf_(r.y);
    r.z *= sigmoidf_(r.z); r.w *= sigmoidf_(r.w);
    *(f4*)(u + (size_t)tok*DI + dq*4) = r;
}

// ---------------- delta = softplus(dt @ Wdt^T + bdt) ----------------
__global__ void __launch_bounds__(256) k_delta(const float* __restrict__ xdbl,
    const float* __restrict__ Wdt, const float* __restrict__ bdt, float* __restrict__ delta)
{
    int d = threadIdx.x;
    int tok0 = blockIdx.x * 16;
    f4 w0 = *(const f4*)(Wdt + d*8);
    f4 w1 = *(const f4*)(Wdt + d*8 + 4);
    float bias = bdt[d];
    __shared__ float dts[16][8];
    if (threadIdx.x < 128){
        int ti = threadIdx.x >> 3, r = threadIdx.x & 7;
        dts[ti][r] = xdbl[(size_t)(tok0+ti)*XDBL_LD + r];
    }
    __syncthreads();
    #pragma unroll 4
    for (int ti=0; ti<16; ++ti){
        f4 d0 = *(const f4*)&dts[ti][0];
        f4 d1 = *(const f4*)&dts[ti][4];
        float v = bias;
        v = fmaf(d0.x,w0.x, v); v = fmaf(d0.y,w0.y, v);
        v = fmaf(d0.z,w0.z, v); v = fmaf(d0.w,w0.w, v);
        v = fmaf(d1.x,w1.x, v); v = fmaf(d1.y,w1.y, v);
        v = fmaf(d1.z,w1.z, v); v = fmaf(d1.w,w1.w, v);
        float sp = (v > 20.f) ? v : log1pf(__expf(v));
        delta[(size_t)(tok0+ti)*DI + d] = sp;
    }
}

// ---------------- scan pass 1: per-group (decay product, local final state) ----------------
// grid: 3584 blocks (XCD x owns batch b=x); block = 4 waves = 4 consecutive d
__global__ void __launch_bounds__(256,8) k_scan1(const float* __restrict__ delta,
    const float* __restrict__ u, const float* __restrict__ xdbl,
    const float* __restrict__ alog, float* __restrict__ hfin, float* __restrict__ aprod)
{
    int bid = blockIdx.x;
    int b = bid & 7;
    int i = bid >> 3;          // 0..447
    int g = i % 7;             // groups 0..6 (last group's state never needed)
    int dblk = i / 7;          // 0..63
    int wave = threadIdx.x >> 6, lane = threadIdx.x & 63;
    int d = dblk*4 + wave;
    int tok0 = b*LSEQ + g*GLEN;
    const float* dptr = delta + (size_t)tok0*DI + d;
    const float* uptr = u     + (size_t)tok0*DI + d;
    const float* xrow = xdbl  + (size_t)tok0*XDBL_LD;
    float Acoef = -__expf(alog[d*DSN + lane]) * 1.44269504f;
    float h = 0.f, cum = 0.f;
    float Bpf[8];
    #pragma unroll
    for (int k=0;k<8;++k) Bpf[k] = xrow[(size_t)k*XDBL_LD + 8 + lane];
    const float* pf = xrow + (size_t)8*XDBL_LD;
    for (int c=0;c<GLEN/64;++c){
        float dv = dptr[(size_t)(c*64+lane)*DI];
        float uv = uptr[(size_t)(c*64+lane)*DI];
        float duv = dv*uv;
        float cs = dv;
        #pragma unroll
        for (int off=32; off; off>>=1) cs += __shfl_xor(cs, off);
        cum += cs;
        #pragma unroll 1
        for (int jj=0;jj<8;++jj){
            #pragma unroll
            for (int k=0;k<8;++k){
                int j = jj*8+k;
                float Bn = Bpf[k];
                Bpf[k] = pf[8+lane];
                pf += XDBL_LD;
                float sd  = __int_as_float(__builtin_amdgcn_readlane(__float_as_int(dv),  j));
                float sdu = __int_as_float(__builtin_amdgcn_readlane(__float_as_int(duv), j));
                float a = exp2f(Acoef*sd);
                h = fmaf(a, h, sdu*Bn);
            }
        }
    }
    size_t idx = ((size_t)(b*DI + d)*GRP + g)*DSN + lane;
    hfin[idx]  = h;
    aprod[idx] = exp2f(Acoef*cum);
}

// ---------------- scan combine: chain group states (8 serial steps per (b,d)) ----------------
__global__ void __launch_bounds__(256) k_comb(const float* __restrict__ hfin,
    const float* __restrict__ aprod, float* __restrict__ hin)
{
    int bd = blockIdx.x*4 + (threadIdx.x>>6);
    int lane = threadIdx.x & 63;
    size_t base = (size_t)bd*GRP*DSN + lane;
    float h = 0.f;
    hin[base] = 0.f;
    #pragma unroll
    for (int g=0; g<GRP-1; ++g){
        float hf = hfin[base + (size_t)g*DSN];
        float ap = aprod[base + (size_t)g*DSN];
        h = fmaf(ap, h, hf);
        hin[base + (size_t)(g+1)*DSN] = h;
    }
}

// ---------------- scan pass 2: full scan per group + gating, writes ygT ----------------
// grid: 4096 blocks (XCD x owns batch b=x); block = 4 waves = 4 consecutive d
__global__ void __launch_bounds__(256,7) k_scan2(const float* __restrict__ delta,
    const float* __restrict__ u, const float* __restrict__ xz,
    const float* __restrict__ xdbl, const float* __restrict__ alog,
    const float* __restrict__ Dp, const float* __restrict__ hin,
    float* __restrict__ ygT)
{
    __shared__ float Q[4][64][17];
    int bid = blockIdx.x;
    int b = bid & 7;
    int i = bid >> 3;          // 0..511
    int g = i & 7;
    int dblk = i >> 3;         // 0..63
    int wave = threadIdx.x >> 6, lane = threadIdx.x & 63;
    int d = dblk*4 + wave;
    int bd = b*DI + d;
    int tok0 = b*LSEQ + g*GLEN;
    float Acoef = -__expf(alog[d*DSN + lane]) * 1.44269504f;
    float Dd = Dp[d];
    float h = hin[((size_t)bd*GRP + g)*DSN + lane];
    const float* dptr = delta + (size_t)tok0*DI + d;
    const float* uptr = u     + (size_t)tok0*DI + d;
    const float* zptr = xz    + (size_t)tok0*2*DI + DI + d;
    const float* xrow = xdbl  + (size_t)tok0*XDBL_LD;
    float* yout = ygT + (size_t)bd*LSEQ + g*GLEN;
    float Bpf[8], Cpf[8];
    #pragma unroll
    for (int k=0;k<8;++k){
        Bpf[k] = xrow[(size_t)k*XDBL_LD + 8 + lane];
        Cpf[k] = xrow[(size_t)k*XDBL_LD + 72 + lane];
    }
    const float* pf = xrow + (size_t)8*XDBL_LD;
    float (*Qw)[17] = Q[wave];
    int q16 = (lane>>4)*16;
    int cidx = lane & 15;
    for (int c=0;c<GLEN/64;++c){
        float dv = dptr[(size_t)(c*64+lane)*DI];
        float uv = uptr[(size_t)(c*64+lane)*DI];
        float zv = zptr[(size_t)(c*64+lane)*2*DI];
        float duv = dv*uv;
        float y = 0.f;
        #pragma unroll 1
        for (int m=0;m<4;++m){
            #pragma unroll
            for (int k=0;k<16;++k){
                int slot = k&7;
                float Bn = Bpf[slot], Cn = Cpf[slot];
                Bpf[slot] = pf[8+lane];
                Cpf[slot] = pf[72+lane];
                pf += XDBL_LD;
                int j = m*16+k;
                float sd  = __int_as_float(__builtin_amdgcn_readlane(__float_as_int(dv),  j));
                float sdu = __int_as_float(__builtin_amdgcn_readlane(__float_as_int(duv), j));
                float a = exp2f(Acoef*sd);
                h = fmaf(a, h, sdu*Bn);
                Qw[lane][k] = h*Cn;
            }
            // column-sum of 16-step micro-tile: 4 lanes per column, then 2 butterflies
            float r = 0.f;
            #pragma unroll
            for (int ii=0;ii<16;++ii) r += Qw[q16+ii][cidx];
            r += __shfl_xor(r, 16);
            r += __shfl_xor(r, 32);
            y = ((lane>>4)==m) ? r : y;
        }
        float yfull = fmaf(uv, Dd, y);
        float yg = yfull * zv * sigmoidf_(zv);
        yout[c*64 + lane] = yg;
    }
}

extern "C" void kernel_launch(void* const* d_in, const int* in_sizes, int n_in,
                              void* d_out, int out_size, void* d_ws, size_t ws_size,
                              hipStream_t stream)
{
    (void)in_sizes; (void)n_in; (void)out_size; (void)ws_size;
    const float* x    = (const float*)d_in[0];
    const float* nw   = (const float*)d_in[1];
    const float* nb   = (const float*)d_in[2];
    const float* w_in = (const float*)d_in[3];
    const float* cw   = (const float*)d_in[4];
    const float* cb   = (const float*)d_in[5];
    const float* wx   = (const float*)d_in[6];
    const float* wdt  = (const float*)d_in[7];
    const float* bdt  = (const float*)d_in[8];
    const float* alog = (const float*)d_in[9];
    const float* Dp   = (const float*)d_in[10];
    const float* wo   = (const float*)d_in[11];
    float* out = (float*)d_out;

    float* ws    = (float*)d_ws;
    float* xz    = ws;                                  // NTOK*512
    float* u     = xz    + (size_t)NTOK*2*DI;           // NTOK*256
    float* xdbl  = u     + (size_t)NTOK*DI;             // NTOK*136 (+slack below)
    float* delta = xdbl  + (size_t)NTOK*XDBL_LD + 4096; // slack for prefetch over-read
    float* ygT   = delta + (size_t)NTOK*DI;             // NTOK*256
    float* stats = ygT   + (size_t)NTOK*DI;             // NTOK*2
    float* hfin  = stats + (size_t)NTOK*2;              // 2048*8*64
    float* aprod = hfin  + (size_t)NB*DI*GRP*DSN;
    float* hin   = aprod + (size_t)NB*DI*GRP*DSN;

    k_lnstats<<<NTOK/4, 256, 0, stream>>>(x, stats);

    dim3 g1(NTOK/64, 8);
    k_gemm<512,128,0><<<g1, 256, 0, stream>>>(x, w_in, xz, 512, stats, nw, nb, nullptr);

    k_conv<<<NTOK*64/256, 256, 0, stream>>>(xz, cw, cb, u);

    dim3 g2(NTOK/64, 3);
    k_gemm<136,256,1><<<g2, 256, 0, stream>>>(u, wx, xdbl, XDBL_LD, nullptr, nullptr, nullptr, nullptr);

    k_delta<<<NTOK/16, 256, 0, stream>>>(xdbl, wdt, bdt, delta);

    k_scan1<<<NB*(GRP-1)*64, 256, 0, stream>>>(delta, u, xdbl, alog, hfin, aprod);
    k_comb<<<NB*DI/4, 256, 0, stream>>>(hfin, aprod, hin);
    k_scan2<<<NB*GRP*64, 256, 0, stream>>>(delta, u, xz, xdbl, alog, Dp, hin, ygT);

    dim3 g3(NTOK/64, 2);
    k_gemm<128,256,2><<<g3, 256, 0, stream>>>(ygT, wo, out, 128, nullptr, nullptr, nullptr, x);
}